// Round 26
// baseline (82.197 us; speedup 1.0000x reference)
//
#include <hip/hip_runtime.h>
#include <hip/hip_bf16.h>

#define NROWS 8192
#define DDIM  512
#define NS    64
#define KK    8
#define HH    240
#define SP    136    // samp pitch, f16 elems (128 + 8 pad)
#define BSTG  4096   // one B stage, ushorts (8 KB)
#define BWOFF 8704   // b1w3 region ushort offset (samp ends at 17408 B)

typedef __attribute__((ext_vector_type(8))) _Float16 f16x8;
typedef __attribute__((ext_vector_type(4))) _Float16 f16x4;
typedef __attribute__((ext_vector_type(4))) float f32x4;

typedef __attribute__((address_space(3))) void       lds_void;
typedef const __attribute__((address_space(1))) void gbl_cvoid;

__device__ inline unsigned pk2u(float a, float b) {
    auto h = __builtin_amdgcn_cvt_pkrtz(a, b);
    unsigned u;
    __builtin_memcpy(&u, &h, sizeof(u));
    return u;
}

__device__ inline f16x4 pk4(float a, float b, float c, float d) {
    uint2 u = make_uint2(pk2u(a, b), pk2u(c, d));
    f16x4 r;
    __builtin_memcpy(&r, &u, sizeof(r));
    return r;
}

__device__ inline f16x8 pk8(float4 lo, float4 hi) {
    uint4 u = make_uint4(pk2u(lo.x, lo.y), pk2u(lo.z, lo.w),
                         pk2u(hi.x, hi.y), pk2u(hi.z, hi.w));
    f16x8 r;
    __builtin_memcpy(&r, &u, sizeof(r));
    return r;
}

__device__ inline void gl16(const ushort* g, ushort* l) {
    __builtin_amdgcn_global_load_lds((gbl_cvoid*)g, (lds_void*)l, 16, 0, 0);
}

// ---------------------------------------------------------------------------
// Kernel 0: pack Th (262144 f) + W1 (122880 f) to f16 + b1w3 table.
// ---------------------------------------------------------------------------
__global__ __launch_bounds__(256)
void pack_kernel(const float* __restrict__ Th, const float* __restrict__ W1,
                 const float* __restrict__ b1, const float* __restrict__ W3,
                 ushort* __restrict__ Thh, ushort* __restrict__ W1h,
                 ushort* __restrict__ bwh)
{
    int t = blockIdx.x * 256 + threadIdx.x;
    if (t < 65536) {
        int i = t * 4;
        float4 v = *(const float4*)(Th + i);
        *(uint2*)(Thh + i) = make_uint2(pk2u(v.x, v.y), pk2u(v.z, v.w));
    } else if (t < 96256) {
        int i = (t - 65536) * 4;
        float4 v = *(const float4*)(W1 + i);
        *(uint2*)(W1h + i) = make_uint2(pk2u(v.x, v.y), pk2u(v.z, v.w));
    } else {
        int j = t - 96256;                 // 0..3839: (s, ht, hi4)
        int s = j / 60, r = j % 60;
        int src = s * HH + (r >> 2) * 16 + (r & 3) * 4;
        float4 b4 = *(const float4*)(b1 + src);
        float4 w4 = *(const float4*)(W3 + src);
        uint4 o = make_uint4(pk2u(b4.x, b4.y), pk2u(b4.z, b4.w),
                             pk2u(w4.x, w4.y), pk2u(w4.z, w4.w));
        *(uint4*)(bwh + j * 8) = o;
    }
}

// ---------------------------------------------------------------------------
// Main fused kernel — r25 minus the A-LDS round-trip:
//  r25 evidence: 1.05M bank conflicts pinned to the f32-A LDS path (identical
//  under two different swizzles). A-frag global footprint is CONTIGUOUS per
//  lane (row = wr+m*16+r16, bytes hi4*32..+32) -> load A f32 DIRECT TO REGS
//  (4x float4/lane/step, 128B-per-row coalescing), cvt 8 pkrtz, pipelined one
//  step ahead. Deletes 2 glf + 2 A ds_reads + all A conflicts per step.
//  B: f16 gl16 2-stage (8KB each), r23-proven 0-conflict layout.
//  b1w3: staged in PROLOGUE (region bytes 17408..32768 disjoint from B
//  stages 0..16384) with OOB fix (r21-25 wrote 1KB past the window).
//  phase 2: acc (+noise) -> f16 samp [64][SP]; phase 3: double-MFMA chain.
// grid = (256, 4); block = 256 (4 waves, 2x2 over 64 rows x 128 cols).
// LDS 32768 B. Reg est ~60 arch (canary: WRITE_SIZE).
// ---------------------------------------------------------------------------
__global__ __launch_bounds__(256, 4)
void proj_mlp_kernel(const float* __restrict__ X,
                     const float* __restrict__ Y,
                     const float* __restrict__ Xn,
                     const ushort* __restrict__ Thh,
                     const ushort* __restrict__ W1h,
                     const ushort* __restrict__ bwh,
                     const float* __restrict__ sig_p,
                     float* __restrict__ sumx,   // [NS][128]
                     float* __restrict__ maxy,   // [NS][128]
                     float* __restrict__ sey)    // [NS][128]
{
    __shared__ __align__(16) ushort smem[16384];     // 32768 B exactly
    ushort* sl = smem;                               // samp [64][SP] (reuse)

    const int tid  = threadIdx.x;
    const int w    = __builtin_amdgcn_readfirstlane(tid >> 6);
    const int lane = tid & 63;
    const int bx   = blockIdx.x;
    const int by   = blockIdx.y;

    const bool isX = (bx < 128);
    const int  bxl = isX ? bx : (bx - 128);
    const float*  srcA = (isX ? X : Y) + (size_t)bxl * 64 * DDIM;
    const ushort* srcB = Thh + (size_t)by * 128 * DDIM;   // [128 rows][512]

    const int wr  = (w >> 1) * 32;
    const int wc  = (w & 1) * 64;
    const int r16 = lane & 15;
    const int hi4 = lane >> 4;

    // A direct-to-reg: frag m covers row wr+m*16+r16, k bytes hi4*32..+32
    const float* gA0 = srcA + (size_t)(wr + r16) * DDIM + hi4 * 8;
    const float* gA1 = srcA + (size_t)(wr + 16 + r16) * DDIM + hi4 * 8;

    // B (f16) gl16 mapping (r23-proven 0-conflict)
    const int grow = (w << 4) + (lane >> 2);
    const int gchk = (lane & 3) ^ ((grow >> 1) & 3);
    const ushort* gB0 = srcB + (size_t)grow * DDIM + gchk * 8;
    const ushort* gB1 = srcB + (size_t)(grow + 64) * DDIM + gchk * 8;
    const int woff = w * 512;

    float4 ra0, ra1, ra2, ra3;
#define LOADA(kf) { const int kA = (kf) * 32; \
    ra0 = *(const float4*)(gA0 + kA);      ra1 = *(const float4*)(gA0 + kA + 4); \
    ra2 = *(const float4*)(gA1 + kA);      ra3 = *(const float4*)(gA1 + kA + 4); }
#define ISSUEB(kf, stU) { const int k_ = (kf) * 32; ushort* s_ = smem + (stU); \
    gl16(gB0 + k_, s_ + woff); \
    gl16(gB1 + k_, s_ + 2048 + woff); }

    f32x4 acc[2][4];
#pragma unroll
    for (int m = 0; m < 2; ++m)
#pragma unroll
        for (int n = 0; n < 4; ++n) acc[m][n] = (f32x4){0.f, 0.f, 0.f, 0.f};

    int offB[4];
#pragma unroll
    for (int n = 0; n < 4; ++n) {
        int row = wc + n * 16 + r16;
        offB[n] = row * 32 + ((hi4 ^ ((row >> 1) & 3)) * 8);
    }

    // prologue: A(0) regs, B(0) stage 0, b1w3 window (disjoint region, OOB-fixed)
    LOADA(0);
    ISSUEB(0, 0);
    {
        const ushort* g = bwh + (size_t)by * 7680;   // 960 chunks used
#pragma unroll
        for (int r = 0; r < 4; ++r) {
            const int ch = r * 256 + w * 64;
            if (ch < 960)
                gl16(g + (size_t)(ch + lane) * 8, smem + BWOFF + ch * 8);
        }
    }

#pragma unroll
    for (int kt = 0; kt < 16; ++kt) {
        asm volatile("s_waitcnt vmcnt(0)\n\ts_barrier" ::: "memory");

        // convert A(t) regs -> frags (before LOADA(t+1) reuses ra)
        f16x8 af[2];
        af[0] = pk8(ra0, ra1);
        af[1] = pk8(ra2, ra3);

        if (kt < 15) {
            ISSUEB(kt + 1, ((kt + 1) & 1) * BSTG);
            LOADA(kt + 1);
        }

        const int cur = (kt & 1) * BSTG;
        f16x8 bfv[4];
#pragma unroll
        for (int n = 0; n < 4; ++n) bfv[n] = *(const f16x8*)(smem + cur + offB[n]);
#pragma unroll
        for (int m = 0; m < 2; ++m)
#pragma unroll
            for (int n = 0; n < 4; ++n)
                acc[m][n] = __builtin_amdgcn_mfma_f32_16x16x32_f16(
                    af[m], bfv[n], acc[m][n], 0, 0, 0);
    }
    __syncthreads();   // all stage reads done before samp aliases them

    // ---- phase 2: acc (+noise) -> f16 samp LDS [64][SP] ---------------------
    const float sig = *sig_p;
    const bool addnoise = (sig > 0.f) && isX;
    const int n0g = bxl * 64;

#pragma unroll
    for (int m = 0; m < 2; ++m)
#pragma unroll
        for (int n = 0; n < 4; ++n) {
            const int col  = wc + n * 16 + r16;
            const int rowb = wr + m * 16 + hi4 * 4;
            float v[4];
#pragma unroll
            for (int j = 0; j < 4; ++j) {
                v[j] = acc[m][n][j];
                if (addnoise)
                    v[j] = fmaf(sig, Xn[(size_t)(n0g + rowb + j) * (NS * KK) + by * 128 + col], v[j]);
            }
            unsigned u01 = pk2u(v[0], v[1]);
            unsigned u23 = pk2u(v[2], v[3]);
            sl[(rowb + 0) * SP + col] = (ushort)u01;
            sl[(rowb + 1) * SP + col] = (ushort)(u01 >> 16);
            sl[(rowb + 2) * SP + col] = (ushort)u23;
            sl[(rowb + 3) * SP + col] = (ushort)(u23 >> 16);
        }
    __syncthreads();

    // ---- phase 3: layer-1 + W3-dot BOTH on MFMA (4 slices/wave) -------------
#pragma unroll 1
    for (int si = 0; si < 4; ++si) {
        const int sloc = w * 4 + si;
        const int s    = by * 16 + sloc;

        f16x4 bsamp[4];
#pragma unroll
        for (int nt = 0; nt < 4; ++nt) {
            f16x4 t = {0, 0, 0, 0};
            if (hi4 < 2)
                t = *(const f16x4*)(sl + (nt * 16 + r16) * SP + sloc * 8 + hi4 * 4);
            bsamp[nt] = t;
        }

        const ushort* w1p = W1h + (size_t)s * HH * KK;

        f32x4 acc2[4];
#pragma unroll
        for (int nt = 0; nt < 4; ++nt) acc2[nt] = (f32x4){0.f, 0.f, 0.f, 0.f};

#pragma unroll 5
        for (int ht = 0; ht < HH / 16; ++ht) {
            f16x4 aw = {0, 0, 0, 0};
            if (hi4 < 2)
                aw = *(const f16x4*)(w1p + (ht * 16 + r16) * 8 + hi4 * 4);
            f16x8 bw = *(const f16x8*)(smem + BWOFF + ((sloc * 15 + ht) * 4 + hi4) * 8);
            f32x4 z = (f32x4){(float)bw[0], (float)bw[1], (float)bw[2], (float)bw[3]};
            f16x4 w3f = {bw[4], bw[5], bw[6], bw[7]};   // A2 frag: W3 chunk
#pragma unroll
            for (int nt = 0; nt < 4; ++nt) {
                f32x4 t = __builtin_amdgcn_mfma_f32_16x16x16f16(aw, bsamp[nt], z, 0, 0, 0);
                f16x4 tb = pk4(fmaxf(t[0], 0.f), fmaxf(t[1], 0.f),
                               fmaxf(t[2], 0.f), fmaxf(t[3], 0.f));
                acc2[nt] = __builtin_amdgcn_mfma_f32_16x16x16f16(w3f, tb, acc2[nt], 0, 0, 0);
            }
        }

        if (isX) {
            float lsum = acc2[0][0] + acc2[1][0] + acc2[2][0] + acc2[3][0];
            lsum += __shfl_xor(lsum, 1);
            lsum += __shfl_xor(lsum, 2);
            lsum += __shfl_xor(lsum, 4);
            lsum += __shfl_xor(lsum, 8);
            if (lane == 0) sumx[s * 128 + bxl] = lsum;
        } else {
            float p[4];
#pragma unroll
            for (int nt = 0; nt < 4; ++nt) p[nt] = acc2[nt][0];
            float M = fmaxf(fmaxf(p[0], p[1]), fmaxf(p[2], p[3]));
            float se = __expf(p[0] - M) + __expf(p[1] - M)
                     + __expf(p[2] - M) + __expf(p[3] - M);
#pragma unroll
            for (int off = 1; off < 16; off <<= 1) {
                float Mo = __shfl_xor(M, off);
                float so = __shfl_xor(se, off);
                float Mm = fmaxf(M, Mo);
                se = se * __expf(M - Mm) + so * __expf(Mo - Mm);
                M = Mm;
            }
            if (lane == 0) {
                maxy[s * 128 + bxl] = M;
                sey[s * 128 + bxl]  = se;
            }
        }
    }
}

// ---------------------------------------------------------------------------
// Final: 256 threads; thread (s, q) covers 32 partials via float4 loads;
// shfl-combine; wave-0 reduces 64 slice terms -> scalar.
// ---------------------------------------------------------------------------
__global__ __launch_bounds__(256)
void final_kernel(const float* __restrict__ sumx,
                  const float* __restrict__ maxy,
                  const float* __restrict__ sey,
                  float* __restrict__ out)
{
    __shared__ float term_s[NS];
    const int tid = threadIdx.x;
    const int s = tid >> 2, q = tid & 3;
    const int base = s * 128 + q * 32;

    float4 sx[8], my[8], sev[8];
#pragma unroll
    for (int i = 0; i < 8; ++i) {
        sx[i]  = *(const float4*)(sumx + base + i * 4);
        my[i]  = *(const float4*)(maxy + base + i * 4);
        sev[i] = *(const float4*)(sey + base + i * 4);
    }

    float sum = 0.f, M = -3.4e38f;
#pragma unroll
    for (int i = 0; i < 8; ++i) {
        sum += (sx[i].x + sx[i].y) + (sx[i].z + sx[i].w);
        M = fmaxf(M, fmaxf(fmaxf(my[i].x, my[i].y), fmaxf(my[i].z, my[i].w)));
    }
    float se = 0.f;
#pragma unroll
    for (int i = 0; i < 8; ++i) {
        se += sev[i].x * __expf(my[i].x - M) + sev[i].y * __expf(my[i].y - M)
            + sev[i].z * __expf(my[i].z - M) + sev[i].w * __expf(my[i].w - M);
    }

#pragma unroll
    for (int off = 1; off < 4; off <<= 1) {
        float Mo = __shfl_xor(M, off);
        float so = __shfl_xor(se, off);
        float su = __shfl_xor(sum, off);
        float Mm = fmaxf(M, Mo);
        se = se * __expf(M - Mm) + so * __expf(Mo - Mm);
        M = Mm;
        sum += su;
    }
    if (q == 0)
        term_s[s] = M + logf(se) - logf((float)NROWS) - sum * (1.0f / (float)NROWS);
    __syncthreads();
    if (tid < 64) {
        float v = term_s[tid];
#pragma unroll
        for (int off = 1; off < 64; off <<= 1) v += __shfl_xor(v, off);
        if (tid == 0) out[0] = v * (1.0f / (float)NS);
    }
}

// ---------------------------------------------------------------------------
extern "C" void kernel_launch(void* const* d_in, const int* in_sizes, int n_in,
                              void* d_out, int out_size, void* d_ws, size_t ws_size,
                              hipStream_t stream)
{
    const float* X   = (const float*)d_in[0];
    const float* Y   = (const float*)d_in[1];
    const float* Xn  = (const float*)d_in[2];
    const float* Th  = (const float*)d_in[3];
    const float* W1  = (const float*)d_in[4];
    const float* b1  = (const float*)d_in[5];
    const float* W3  = (const float*)d_in[6];
    // d_in[7] = b3: cancels exactly between mean_x and LSE_y -> unused
    const float* sig = (const float*)d_in[8];

    ushort* Thh  = (ushort*)d_ws;                     // 262,144 f16
    ushort* W1h  = Thh + 262144;                      // 122,880 f16
    ushort* bwh  = W1h + 122880;                      // b1w3 table (30720 used)
    float*  sumx = (float*)(bwh + 61440);
    float*  maxy = sumx + NS * 128;
    float*  sey  = maxy + NS * 128;

    pack_kernel<<<391, 256, 0, stream>>>(Th, W1, b1, W3, Thh, W1h, bwh);

    dim3 g1(256, 4, 1);
    proj_mlp_kernel<<<g1, 256, 0, stream>>>(X, Y, Xn, Thh, W1h, bwh,
                                            sig, sumx, maxy, sey);
    final_kernel<<<1, 256, 0, stream>>>(sumx, maxy, sey, (float*)d_out);
}

// Round 27
// 62.330 us; speedup vs baseline: 1.3187x; 1.3187x over previous
//
#include <hip/hip_runtime.h>
#include <hip/hip_bf16.h>

#define NROWS 8192
#define DDIM  512
#define NS    64
#define KK    8
#define HH    240
#define SP    136    // samp pitch, f16 elems (128 + 8 pad)
#define BOFFU 4096   // B region ushort offset within stage (A-f32 = 8 KB)
#define STGU  8192   // stage size in ushorts (16 KB)
#define BWOFF 8704   // b1w3 region ushort offset (samp ends at 17408 B)

typedef __attribute__((ext_vector_type(8))) _Float16 f16x8;
typedef __attribute__((ext_vector_type(4))) _Float16 f16x4;
typedef __attribute__((ext_vector_type(4))) float f32x4;

typedef __attribute__((address_space(3))) void       lds_void;
typedef const __attribute__((address_space(1))) void gbl_cvoid;

__device__ inline unsigned pk2u(float a, float b) {
    auto h = __builtin_amdgcn_cvt_pkrtz(a, b);
    unsigned u;
    __builtin_memcpy(&u, &h, sizeof(u));
    return u;
}

__device__ inline f16x4 pk4(float a, float b, float c, float d) {
    uint2 u = make_uint2(pk2u(a, b), pk2u(c, d));
    f16x4 r;
    __builtin_memcpy(&r, &u, sizeof(r));
    return r;
}

__device__ inline void gl16(const ushort* g, ushort* l) {
    __builtin_amdgcn_global_load_lds((gbl_cvoid*)g, (lds_void*)l, 16, 0, 0);
}
__device__ inline void glf(const float* g, ushort* l) {
    __builtin_amdgcn_global_load_lds((gbl_cvoid*)g, (lds_void*)l, 16, 0, 0);
}

// ---------------------------------------------------------------------------
// Kernel 0: pack Th (262144 f) + W1 (122880 f) to f16 + b1w3 table.
// ---------------------------------------------------------------------------
__global__ __launch_bounds__(256)
void pack_kernel(const float* __restrict__ Th, const float* __restrict__ W1,
                 const float* __restrict__ b1, const float* __restrict__ W3,
                 ushort* __restrict__ Thh, ushort* __restrict__ W1h,
                 ushort* __restrict__ bwh)
{
    int t = blockIdx.x * 256 + threadIdx.x;
    if (t < 65536) {
        int i = t * 4;
        float4 v = *(const float4*)(Th + i);
        *(uint2*)(Thh + i) = make_uint2(pk2u(v.x, v.y), pk2u(v.z, v.w));
    } else if (t < 96256) {
        int i = (t - 65536) * 4;
        float4 v = *(const float4*)(W1 + i);
        *(uint2*)(W1h + i) = make_uint2(pk2u(v.x, v.y), pk2u(v.z, v.w));
    } else {
        int j = t - 96256;                 // 0..3839: (s, ht, hi4)
        int s = j / 60, r = j % 60;
        int src = s * HH + (r >> 2) * 16 + (r & 3) * 4;
        float4 b4 = *(const float4*)(b1 + src);
        float4 w4 = *(const float4*)(W3 + src);
        uint4 o = make_uint4(pk2u(b4.x, b4.y), pk2u(b4.z, b4.w),
                             pk2u(w4.x, w4.y), pk2u(w4.z, w4.w));
        *(uint4*)(bwh + j * 8) = o;
    }
}

// ---------------------------------------------------------------------------
// Main fused kernel — r25 verbatim (best measured: main 59.4 us) + OOB guard:
//  phase 1: samp 64x128. BK=32, 2-stage dbuf (A-f32 8KB | B-f16 8KB),
//           {wait vmcnt(0); barrier; issue L(t+1); compute}; A staged f32 via
//           gl16, frag = 2x ds_read_b128 + 4 pkrtz. (r26's A-direct-to-reg
//           regressed 59->77; the ~1.05M conflict count = 1 cyc/wave/step =
//           trivial, NOT worth chasing — r24 errata.)
//  phase 2: acc (+noise) -> f16 samp LDS [64][SP]; b1w3 staged async (960-
//           chunk window, OOB-guarded).
//  phase 3: double-MFMA chain (W1 mfma -> relu/cvt -> W3 mfma).
// grid = (256, 4); block = 256. LDS 32768 B exactly.
// ---------------------------------------------------------------------------
__global__ __launch_bounds__(256, 4)
void proj_mlp_kernel(const float* __restrict__ X,
                     const float* __restrict__ Y,
                     const float* __restrict__ Xn,
                     const ushort* __restrict__ Thh,
                     const ushort* __restrict__ W1h,
                     const ushort* __restrict__ bwh,
                     const float* __restrict__ sig_p,
                     float* __restrict__ sumx,   // [NS][128]
                     float* __restrict__ maxy,   // [NS][128]
                     float* __restrict__ sey)    // [NS][128]
{
    __shared__ __align__(16) ushort smem[16384];     // 32768 B exactly
    ushort* sl = smem;                               // samp [64][SP] (reuse)

    const int tid  = threadIdx.x;
    const int w    = __builtin_amdgcn_readfirstlane(tid >> 6);
    const int lane = tid & 63;
    const int bx   = blockIdx.x;
    const int by   = blockIdx.y;

    const bool isX = (bx < 128);
    const int  bxl = isX ? bx : (bx - 128);
    const float*  srcA = (isX ? X : Y) + (size_t)bxl * 64 * DDIM;
    const ushort* srcB = Thh + (size_t)by * 128 * DDIM;   // [128 rows][512]

    // A (f32) gl16 mapping: lane -> row 16w+(l>>2), slot (l&3), chunk slot^asw
    const int arow = (w << 4) + (lane >> 2);
    const int asw  = (arow >> 1) & 3;
    const float* gA0 = srcA + (size_t)arow * DDIM + (((lane & 3) ^ asw) + 0) * 4;
    const float* gA1 = srcA + (size_t)arow * DDIM + (((lane & 3) ^ asw) + 4) * 4;

    // B (f16) gl16 mapping (r23-proven)
    const int grow = (w << 4) + (lane >> 2);
    const int gchk = (lane & 3) ^ ((grow >> 1) & 3);
    const ushort* gB0 = srcB + (size_t)grow * DDIM + gchk * 8;
    const ushort* gB1 = srcB + (size_t)(grow + 64) * DDIM + gchk * 8;
    const int woff = w * 512;

#define ISSUE(kf, stU) { const int k_ = (kf) * 32; ushort* s_ = smem + (stU); \
    glf(gA0 + k_, s_ + w * 1024); \
    glf(gA1 + k_, s_ + w * 1024 + 512); \
    gl16(gB0 + k_, s_ + BOFFU + woff); \
    gl16(gB1 + k_, s_ + BOFFU + 2048 + woff); }

    f32x4 acc[2][4];
#pragma unroll
    for (int m = 0; m < 2; ++m)
#pragma unroll
        for (int n = 0; n < 4; ++n) acc[m][n] = (f32x4){0.f, 0.f, 0.f, 0.f};

    const int wr  = (w >> 1) * 32;
    const int wc  = (w & 1) * 64;
    const int r16 = lane & 15;
    const int hi4 = lane >> 4;

    int offA32[2][2];
#pragma unroll
    for (int m = 0; m < 2; ++m) {
        int row = wr + m * 16 + r16;
        int sw  = (row >> 1) & 3;
#pragma unroll
        for (int cc = 0; cc < 2; ++cc) {
            int c = hi4 * 2 + cc;
            int p = (c & 4) | ((c & 3) ^ sw);
            offA32[m][cc] = (row >> 4) * 2048 + (p >> 2) * 1024
                          + (row & 15) * 64 + (p & 3) * 16;
        }
    }
    int offB[4];
#pragma unroll
    for (int n = 0; n < 4; ++n) {
        int row = wc + n * 16 + r16;
        offB[n] = BOFFU + row * 32 + ((hi4 ^ ((row >> 1) & 3)) * 8);
    }

    // prologue: issue tile 0 into stage 0
    ISSUE(0, 0);

#pragma unroll
    for (int kt = 0; kt < 16; ++kt) {
        asm volatile("s_waitcnt vmcnt(0)\n\ts_barrier" ::: "memory");

        if (kt < 15) ISSUE(kt + 1, ((kt + 1) & 1) * STGU);

        const int curU = (kt & 1) * STGU;
        const char* curB = (const char*)smem + (kt & 1) * 16384;

        f16x8 af[2], bfv[4];
#pragma unroll
        for (int m = 0; m < 2; ++m) {
            f32x4 lo = *(const f32x4*)(curB + offA32[m][0]);
            f32x4 hi = *(const f32x4*)(curB + offA32[m][1]);
            uint4 u = make_uint4(pk2u(lo[0], lo[1]), pk2u(lo[2], lo[3]),
                                 pk2u(hi[0], hi[1]), pk2u(hi[2], hi[3]));
            __builtin_memcpy(&af[m], &u, 16);
        }
#pragma unroll
        for (int n = 0; n < 4; ++n) bfv[n] = *(const f16x8*)(smem + curU + offB[n]);
#pragma unroll
        for (int m = 0; m < 2; ++m)
#pragma unroll
            for (int n = 0; n < 4; ++n)
                acc[m][n] = __builtin_amdgcn_mfma_f32_16x16x32_f16(
                    af[m], bfv[n], acc[m][n], 0, 0, 0);
    }
    __syncthreads();   // all stage reads done before samp/bw alias them

    // ---- async-stage b1w3 window (overlaps phase 2; 960 chunks, guarded) ----
    {
        const ushort* g = bwh + (size_t)by * 7680;
#pragma unroll
        for (int r = 0; r < 4; ++r) {
            const int ch = r * 256 + w * 64;
            if (ch < 960)
                gl16(g + (size_t)(ch + lane) * 8, smem + BWOFF + ch * 8);
        }
    }

    // ---- phase 2: acc (+noise) -> f16 samp LDS [64][SP] ---------------------
    const float sig = *sig_p;
    const bool addnoise = (sig > 0.f) && isX;
    const int n0g = bxl * 64;

#pragma unroll
    for (int m = 0; m < 2; ++m)
#pragma unroll
        for (int n = 0; n < 4; ++n) {
            const int col  = wc + n * 16 + r16;
            const int rowb = wr + m * 16 + hi4 * 4;
            float v[4];
#pragma unroll
            for (int j = 0; j < 4; ++j) {
                v[j] = acc[m][n][j];
                if (addnoise)
                    v[j] = fmaf(sig, Xn[(size_t)(n0g + rowb + j) * (NS * KK) + by * 128 + col], v[j]);
            }
            unsigned u01 = pk2u(v[0], v[1]);
            unsigned u23 = pk2u(v[2], v[3]);
            sl[(rowb + 0) * SP + col] = (ushort)u01;
            sl[(rowb + 1) * SP + col] = (ushort)(u01 >> 16);
            sl[(rowb + 2) * SP + col] = (ushort)u23;
            sl[(rowb + 3) * SP + col] = (ushort)(u23 >> 16);
        }
    asm volatile("s_waitcnt vmcnt(0)" ::: "memory");   // b1w3 gl16 landed
    __syncthreads();

    // ---- phase 3: layer-1 + W3-dot BOTH on MFMA (4 slices/wave) -------------
#pragma unroll 1
    for (int si = 0; si < 4; ++si) {
        const int sloc = w * 4 + si;
        const int s    = by * 16 + sloc;

        f16x4 bsamp[4];
#pragma unroll
        for (int nt = 0; nt < 4; ++nt) {
            f16x4 t = {0, 0, 0, 0};
            if (hi4 < 2)
                t = *(const f16x4*)(sl + (nt * 16 + r16) * SP + sloc * 8 + hi4 * 4);
            bsamp[nt] = t;
        }

        const ushort* w1p = W1h + (size_t)s * HH * KK;

        f32x4 acc2[4];
#pragma unroll
        for (int nt = 0; nt < 4; ++nt) acc2[nt] = (f32x4){0.f, 0.f, 0.f, 0.f};

#pragma unroll 5
        for (int ht = 0; ht < HH / 16; ++ht) {
            f16x4 aw = {0, 0, 0, 0};
            if (hi4 < 2)
                aw = *(const f16x4*)(w1p + (ht * 16 + r16) * 8 + hi4 * 4);
            f16x8 bw = *(const f16x8*)(smem + BWOFF + ((sloc * 15 + ht) * 4 + hi4) * 8);
            f32x4 z = (f32x4){(float)bw[0], (float)bw[1], (float)bw[2], (float)bw[3]};
            f16x4 w3f = {bw[4], bw[5], bw[6], bw[7]};   // A2 frag: W3 chunk
#pragma unroll
            for (int nt = 0; nt < 4; ++nt) {
                f32x4 t = __builtin_amdgcn_mfma_f32_16x16x16f16(aw, bsamp[nt], z, 0, 0, 0);
                f16x4 tb = pk4(fmaxf(t[0], 0.f), fmaxf(t[1], 0.f),
                               fmaxf(t[2], 0.f), fmaxf(t[3], 0.f));
                acc2[nt] = __builtin_amdgcn_mfma_f32_16x16x16f16(w3f, tb, acc2[nt], 0, 0, 0);
            }
        }

        if (isX) {
            float lsum = acc2[0][0] + acc2[1][0] + acc2[2][0] + acc2[3][0];
            lsum += __shfl_xor(lsum, 1);
            lsum += __shfl_xor(lsum, 2);
            lsum += __shfl_xor(lsum, 4);
            lsum += __shfl_xor(lsum, 8);
            if (lane == 0) sumx[s * 128 + bxl] = lsum;
        } else {
            float p[4];
#pragma unroll
            for (int nt = 0; nt < 4; ++nt) p[nt] = acc2[nt][0];
            float M = fmaxf(fmaxf(p[0], p[1]), fmaxf(p[2], p[3]));
            float se = __expf(p[0] - M) + __expf(p[1] - M)
                     + __expf(p[2] - M) + __expf(p[3] - M);
#pragma unroll
            for (int off = 1; off < 16; off <<= 1) {
                float Mo = __shfl_xor(M, off);
                float so = __shfl_xor(se, off);
                float Mm = fmaxf(M, Mo);
                se = se * __expf(M - Mm) + so * __expf(Mo - Mm);
                M = Mm;
            }
            if (lane == 0) {
                maxy[s * 128 + bxl] = M;
                sey[s * 128 + bxl]  = se;
            }
        }
    }
}

// ---------------------------------------------------------------------------
// Final: 1024 threads (was 256 — single-CU latency-bound at ~4.6 us with 24
// dependent float4 loads/thread). Now 16 threads/slice, 6 float4 each,
// 16-lane shfl combine, wave-0 finish. Single launch.
// ---------------------------------------------------------------------------
__global__ __launch_bounds__(1024)
void final_kernel(const float* __restrict__ sumx,
                  const float* __restrict__ maxy,
                  const float* __restrict__ sey,
                  float* __restrict__ out)
{
    __shared__ float term_s[NS];
    const int tid = threadIdx.x;
    const int s = tid >> 4, q = tid & 15;      // slice, 16-way split
    const int base = s * 128 + q * 8;

    float4 sx0 = *(const float4*)(sumx + base);
    float4 sx1 = *(const float4*)(sumx + base + 4);
    float4 my0 = *(const float4*)(maxy + base);
    float4 my1 = *(const float4*)(maxy + base + 4);
    float4 se0 = *(const float4*)(sey + base);
    float4 se1 = *(const float4*)(sey + base + 4);

    float sum = (sx0.x + sx0.y) + (sx0.z + sx0.w)
              + (sx1.x + sx1.y) + (sx1.z + sx1.w);
    float M = fmaxf(fmaxf(fmaxf(my0.x, my0.y), fmaxf(my0.z, my0.w)),
                    fmaxf(fmaxf(my1.x, my1.y), fmaxf(my1.z, my1.w)));
    float se = se0.x * __expf(my0.x - M) + se0.y * __expf(my0.y - M)
             + se0.z * __expf(my0.z - M) + se0.w * __expf(my0.w - M)
             + se1.x * __expf(my1.x - M) + se1.y * __expf(my1.y - M)
             + se1.z * __expf(my1.z - M) + se1.w * __expf(my1.w - M);

#pragma unroll
    for (int off = 1; off < 16; off <<= 1) {
        float Mo = __shfl_xor(M, off);
        float so = __shfl_xor(se, off);
        float su = __shfl_xor(sum, off);
        float Mm = fmaxf(M, Mo);
        se = se * __expf(M - Mm) + so * __expf(Mo - Mm);
        M = Mm;
        sum += su;
    }
    if (q == 0)
        term_s[s] = M + logf(se) - logf((float)NROWS) - sum * (1.0f / (float)NROWS);
    __syncthreads();
    if (tid < 64) {
        float v = term_s[tid];
#pragma unroll
        for (int off = 1; off < 64; off <<= 1) v += __shfl_xor(v, off);
        if (tid == 0) out[0] = v * (1.0f / (float)NS);
    }
}

// ---------------------------------------------------------------------------
extern "C" void kernel_launch(void* const* d_in, const int* in_sizes, int n_in,
                              void* d_out, int out_size, void* d_ws, size_t ws_size,
                              hipStream_t stream)
{
    const float* X   = (const float*)d_in[0];
    const float* Y   = (const float*)d_in[1];
    const float* Xn  = (const float*)d_in[2];
    const float* Th  = (const float*)d_in[3];
    const float* W1  = (const float*)d_in[4];
    const float* b1  = (const float*)d_in[5];
    const float* W3  = (const float*)d_in[6];
    // d_in[7] = b3: cancels exactly between mean_x and LSE_y -> unused
    const float* sig = (const float*)d_in[8];

    ushort* Thh  = (ushort*)d_ws;                     // 262,144 f16
    ushort* W1h  = Thh + 262144;                      // 122,880 f16
    ushort* bwh  = W1h + 122880;                      // b1w3 table (30720 used)
    float*  sumx = (float*)(bwh + 61440);
    float*  maxy = sumx + NS * 128;
    float*  sey  = maxy + NS * 128;

    pack_kernel<<<391, 256, 0, stream>>>(Th, W1, b1, W3, Thh, W1h, bwh);

    dim3 g1(256, 4, 1);
    proj_mlp_kernel<<<g1, 256, 0, stream>>>(X, Y, Xn, Thh, W1h, bwh,
                                            sig, sumx, maxy, sey);
    final_kernel<<<1, 1024, 0, stream>>>(sumx, maxy, sey, (float*)d_out);
}